// Round 2
// baseline (605.208 us; speedup 1.0000x reference)
//
#include <hip/hip_runtime.h>
#include <math.h>

#define N 16384
#define D 23
#define K 16
#define JS 8
#define CH 2048              // chunk size = N/JS
#define NBATCH 128           // CH/16
#define NBUCK 1024
#define XRANGE 16.0f         // keys clamped to [-16,16): 16-sigma safe for N(0,1) data
#define BSCALE (NBUCK / (2.0f * XRANGE))   // 32 buckets per unit
#define DLT (1.0f / BSCALE)                // bucket width = conservative slack

__device__ __forceinline__ int bucket_of(float x) {
  int b = (int)((x + XRANGE) * BSCALE);
  return b < 0 ? 0 : (b > NBUCK - 1 ? NBUCK - 1 : b);
}

// Sorted ascending insert of (d2, jj) into register arrays vald/vali (K deep).
// Caller guarantees d2 < vald[K-1].
#define TOPK_INSERT(vald, vali, d2v, jjv)                          \
  {                                                                \
    bool ck = true;                                                \
    _Pragma("unroll") for (int k = K - 1; k >= 0; --k) {           \
      bool ckm1 = (k > 0) ? ((d2v) < vald[k - 1]) : false;         \
      float nv = ckm1 ? vald[k - 1] : (ck ? (d2v) : vald[k]);      \
      int ni = ckm1 ? vali[k - 1] : (ck ? (jjv) : vali[k]);        \
      vald[k] = nv;                                                \
      vali[k] = ni;                                                \
      ck = ckm1;                                                   \
    }                                                              \
  }

// ---------------------------------------------------------------------------
// Kernel 0: zero bucket counters (hist + cnt2)
// ---------------------------------------------------------------------------
__global__ __launch_bounds__(256) void zero_kernel(int* __restrict__ hist,
                                                   int* __restrict__ cnt2) {
  for (int t = threadIdx.x; t < NBUCK; t += 256) {
    hist[t] = 0;
    cnt2[t] = 0;
  }
}

// ---------------------------------------------------------------------------
// Kernel 1: s = x@W_s + b_s, h = x@W_h + b_h; pack s4={sx,sy,sz,sq}, h4;
//           histogram of x-buckets.
// ---------------------------------------------------------------------------
__global__ __launch_bounds__(64) void prep_kernel(
    const float* __restrict__ x, const float* __restrict__ Ws,
    const float* __restrict__ bs, const float* __restrict__ Wh,
    const float* __restrict__ bh, float4* __restrict__ s4,
    float4* __restrict__ h4, int* __restrict__ hist) {
  __shared__ float lWs[D * 3], lWh[D * 3], lbs[3], lbh[3];
  for (int t = threadIdx.x; t < D * 3; t += 64) {
    lWs[t] = Ws[t];
    lWh[t] = Wh[t];
  }
  if (threadIdx.x < 3) {
    lbs[threadIdx.x] = bs[threadIdx.x];
    lbh[threadIdx.x] = bh[threadIdx.x];
  }
  __syncthreads();

  int i = blockIdx.x * 64 + threadIdx.x;
  float a0 = 0.f, a1 = 0.f, a2 = 0.f;
  float g0 = 0.f, g1 = 0.f, g2 = 0.f;
#pragma unroll
  for (int d = 0; d < D; ++d) {
    float xv = x[i * D + d];
    a0 = fmaf(xv, lWs[d * 3 + 0], a0);
    a1 = fmaf(xv, lWs[d * 3 + 1], a1);
    a2 = fmaf(xv, lWs[d * 3 + 2], a2);
    g0 = fmaf(xv, lWh[d * 3 + 0], g0);
    g1 = fmaf(xv, lWh[d * 3 + 1], g1);
    g2 = fmaf(xv, lWh[d * 3 + 2], g2);
  }
  float s0 = __fadd_rn(a0, lbs[0]);
  float s1 = __fadd_rn(a1, lbs[1]);
  float s2 = __fadd_rn(a2, lbs[2]);
  float sq = fmaf(s2, s2, fmaf(s1, s1, __fmul_rn(s0, s0)));
  s4[i] = make_float4(s0, s1, s2, sq);
  h4[i] = make_float4(__fadd_rn(g0, lbh[0]), __fadd_rn(g1, lbh[1]),
                      __fadd_rn(g2, lbh[2]), 0.f);
  atomicAdd(&hist[bucket_of(s0)], 1);
}

// ---------------------------------------------------------------------------
// Kernel 2: exclusive prefix sum of hist[1024] -> offs[1024]. One block.
// ---------------------------------------------------------------------------
__global__ __launch_bounds__(256) void scan_kernel(const int* __restrict__ hist,
                                                   int* __restrict__ offs) {
  __shared__ int arr[NBUCK];
  __shared__ int tsum[256];
  int t = threadIdx.x;
#pragma unroll
  for (int j = 0; j < 4; ++j) arr[t * 4 + j] = hist[t * 4 + j];
  __syncthreads();
  int s = arr[t * 4] + arr[t * 4 + 1] + arr[t * 4 + 2] + arr[t * 4 + 3];
  tsum[t] = s;
  __syncthreads();
  for (int off = 1; off < 256; off <<= 1) {
    int v = (t >= off) ? tsum[t - off] : 0;
    __syncthreads();
    tsum[t] += v;
    __syncthreads();
  }
  int base = tsum[t] - s;  // exclusive
  offs[t * 4 + 0] = base;
  offs[t * 4 + 1] = base + arr[t * 4];
  offs[t * 4 + 2] = base + arr[t * 4] + arr[t * 4 + 1];
  offs[t * 4 + 3] = base + arr[t * 4] + arr[t * 4 + 1] + arr[t * 4 + 2];
}

// ---------------------------------------------------------------------------
// Kernel 3: scatter into x-sorted, chunk-decimated layout.
//   sorted pos -> dpos = (pos % JS)*CH + pos/JS
// ---------------------------------------------------------------------------
__global__ __launch_bounds__(64) void scatter_kernel(
    const float4* __restrict__ s4, const int* __restrict__ offs,
    int* __restrict__ cnt2, float4* __restrict__ s4s,
    int* __restrict__ idxs) {
  int i = blockIdx.x * 64 + threadIdx.x;
  float4 s = s4[i];
  int b = bucket_of(s.x);
  int pos = offs[b] + atomicAdd(&cnt2[b], 1);
  int dpos = (pos & (JS - 1)) * CH + (pos >> 3);
  s4s[dpos] = s;
  idxs[dpos] = i;
}

// ---------------------------------------------------------------------------
// Kernel 4: kNN. Block = 256 threads (4 waves), grid = 64 qgroups * JS chunks.
// Each wave: 64 consecutive sorted queries; walks its chunk outward from its
// own x-position; per-16-candidate batch early-break when all lanes certify
// gap^2 > current 16th-best (conservative bucket-slack bound -> exact).
// ---------------------------------------------------------------------------
__global__ __launch_bounds__(256) void knn_kernel(
    const float4* __restrict__ s4s, unsigned short* __restrict__ pidx) {
  __shared__ float4 tile[CH];  // 32 KB
  int qg = blockIdx.x >> 3;    // query group (256 queries)
  int c = blockIdx.x & (JS - 1);
  for (int t = threadIdx.x; t < CH; t += 256) tile[t] = s4s[c * CH + t];
  __syncthreads();

  int wid = threadIdx.x >> 6;
  int P = qg * 256 + threadIdx.x;  // sorted query pos
  int dq = (P & (JS - 1)) * CH + (P >> 3);
  float4 si = s4s[dq];
  float sqi = si.w;

  float vd[K];
  int vi[K];
#pragma unroll
  for (int k = 0; k < K; ++k) {
    vd[k] = INFINITY;
    vi[k] = 0;
  }

  int dcbase = c * CH;
  int bstart = (qg * 256 + wid * 64 + 32) >> 7;  // /JS(8) /16 -> batch idx
  if (bstart > NBATCH - 1) bstart = NBATCH - 1;

  // right walk
  for (int b = bstart; b < NBATCH; ++b) {
    float xlo = tile[b * 16].x - DLT;  // lower bound on ALL elems >= this batch
    float g = xlo - si.x;
    if (__all(g > 0.f && g * g > vd[K - 1])) break;
#pragma unroll
    for (int u = 0; u < 16; ++u) {
      float4 sj = tile[b * 16 + u];
      float dot = fmaf(si.z, sj.z, fmaf(si.y, sj.y, __fmul_rn(si.x, sj.x)));
      float d2 = __fsub_rn(__fadd_rn(sqi, sj.w), __fmul_rn(2.0f, dot));
      if (d2 < vd[K - 1]) {
        int jj = dcbase + b * 16 + u;
        TOPK_INSERT(vd, vi, d2, jj);
      }
    }
  }
  // left walk
  for (int b = bstart - 1; b >= 0; --b) {
    float xhi = tile[b * 16 + 15].x + DLT;  // upper bound on ALL elems <= batch
    float g = si.x - xhi;
    if (__all(g > 0.f && g * g > vd[K - 1])) break;
#pragma unroll
    for (int u = 0; u < 16; ++u) {
      float4 sj = tile[b * 16 + u];
      float dot = fmaf(si.z, sj.z, fmaf(si.y, sj.y, __fmul_rn(si.x, sj.x)));
      float d2 = __fsub_rn(__fadd_rn(sqi, sj.w), __fmul_rn(2.0f, dot));
      if (d2 < vd[K - 1]) {
        int jj = dcbase + b * 16 + u;
        TOPK_INSERT(vd, vi, d2, jj);
      }
    }
  }

#pragma unroll
  for (int k = 0; k < K; ++k)
    pidx[(size_t)(c * K + k) * N + P] = (unsigned short)vi[k];
}

// ---------------------------------------------------------------------------
// Kernel 5: merge JS partial lists (d2 recomputed bitwise-identically),
// weights, gather h, mean/max aggregate -> aggr[orig][8].
// ---------------------------------------------------------------------------
__global__ __launch_bounds__(256) void merge_kernel(
    const float4* __restrict__ s4s, const int* __restrict__ idxs,
    const float4* __restrict__ h4, const unsigned short* __restrict__ pidx,
    float* __restrict__ aggr) {
  int P = blockIdx.x * 256 + threadIdx.x;
  int dq = (P & (JS - 1)) * CH + (P >> 3);
  float4 si = s4s[dq];
  float sqi = si.w;

  float vd[K];
  int vi[K];
#pragma unroll
  for (int k = 0; k < K; ++k) {
    vd[k] = INFINITY;
    vi[k] = 0;
  }
  // k-outer, chunk-inner: first 8 reads are the 8 chunk minima (fast warm-up)
  for (int k = 0; k < K; ++k) {
    for (int c = 0; c < JS; ++c) {
      int dc = pidx[(size_t)(c * K + k) * N + P];
      float4 sj = s4s[dc];
      float dot = fmaf(si.z, sj.z, fmaf(si.y, sj.y, __fmul_rn(si.x, sj.x)));
      float d2 = __fsub_rn(__fadd_rn(sqi, sj.w), __fmul_rn(2.0f, dot));
      if (d2 < vd[K - 1]) {
        TOPK_INSERT(vd, vi, d2, dc);
      }
    }
  }

  float m0 = 0.f, m1 = 0.f, m2 = 0.f;
  float x0 = -INFINITY, x1 = -INFINITY, x2 = -INFINITY;
#pragma unroll
  for (int k = 0; k < K; ++k) {
    float d2c = fmaxf(vd[k], 0.f);
    float w = expf(-10.0f * d2c);
    int orig = idxs[vi[k]];
    float4 hh = h4[orig];
    float v0 = __fmul_rn(hh.x, w);
    float v1 = __fmul_rn(hh.y, w);
    float v2 = __fmul_rn(hh.z, w);
    m0 += v0; m1 += v1; m2 += v2;
    x0 = fmaxf(x0, v0); x1 = fmaxf(x1, v1); x2 = fmaxf(x2, v2);
  }
  const float inv = 1.0f / (float)K;
  int oq = idxs[dq];
  aggr[(size_t)oq * 8 + 0] = m0 * inv;
  aggr[(size_t)oq * 8 + 1] = m1 * inv;
  aggr[(size_t)oq * 8 + 2] = m2 * inv;
  aggr[(size_t)oq * 8 + 3] = x0;
  aggr[(size_t)oq * 8 + 4] = x1;
  aggr[(size_t)oq * 8 + 5] = x2;
}

// ---------------------------------------------------------------------------
// Kernel 6: latent = x@W_o1 + (aggr@W_o2 + b_o2); beta = clip(sigmoid(...))
// ---------------------------------------------------------------------------
__global__ __launch_bounds__(64) void out_kernel(
    const float* __restrict__ x, const float* __restrict__ aggr,
    const float* __restrict__ Wo1, const float* __restrict__ Wo2,
    const float* __restrict__ bo2, const float* __restrict__ Wb,
    const float* __restrict__ bb, float* __restrict__ out) {
  __shared__ float lWo1[D * D];
  __shared__ float lWo2[6 * D];
  __shared__ float lbo2[D], lWb[D];
  __shared__ float lbb;
  for (int t = threadIdx.x; t < D * D; t += 64) lWo1[t] = Wo1[t];
  for (int t = threadIdx.x; t < 6 * D; t += 64) lWo2[t] = Wo2[t];
  if (threadIdx.x < D) {
    lbo2[threadIdx.x] = bo2[threadIdx.x];
    lWb[threadIdx.x] = Wb[threadIdx.x];
  }
  if (threadIdx.x == 0) lbb = bb[0];
  __syncthreads();

  int i = blockIdx.x * 64 + threadIdx.x;
  float xr[D];
#pragma unroll
  for (int d = 0; d < D; ++d) xr[d] = x[i * D + d];
  float ag[6];
#pragma unroll
  for (int p = 0; p < 6; ++p) ag[p] = aggr[(size_t)i * 8 + p];

  float z = 0.f;
#pragma unroll
  for (int o = 0; o < D; ++o) {
    float a = 0.f;
#pragma unroll
    for (int d = 0; d < D; ++d) a = fmaf(xr[d], lWo1[d * D + o], a);
    float b2 = 0.f;
#pragma unroll
    for (int p = 0; p < 6; ++p) b2 = fmaf(ag[p], lWo2[p * D + o], b2);
    b2 = __fadd_rn(b2, lbo2[o]);
    float lat = __fadd_rn(a, b2);
    out[(size_t)N + (size_t)i * D + o] = lat;
    z = fmaf(lat, lWb[o], z);
  }
  z = __fadd_rn(z, lbb);
  float beta = 1.0f / (1.0f + expf(-z));
  beta = fminf(fmaxf(beta, 1e-6f), 1.0f - 1e-6f);
  out[i] = beta;
}

// ---------------------------------------------------------------------------
extern "C" void kernel_launch(void* const* d_in, const int* in_sizes, int n_in,
                              void* d_out, int out_size, void* d_ws,
                              size_t ws_size, hipStream_t stream) {
  const float* x = (const float*)d_in[0];
  const float* Ws = (const float*)d_in[1];
  const float* bs = (const float*)d_in[2];
  const float* Wh = (const float*)d_in[3];
  const float* bh = (const float*)d_in[4];
  const float* Wo1 = (const float*)d_in[5];
  const float* Wo2 = (const float*)d_in[6];
  const float* bo2 = (const float*)d_in[7];
  const float* Wb = (const float*)d_in[8];
  const float* bb = (const float*)d_in[9];
  float* out = (float*)d_out;

  // ws layout (all 16B-aligned):
  // s4[N*4]f | h4[N*4]f | s4s[N*4]f | aggr[N*8]f | idxs[N]i | hist[1024]i |
  // cnt2[1024]i | offs[1024]i | pidx[N*128]u16        (~5.6 MB total)
  float* ws = (float*)d_ws;
  float4* s4 = (float4*)ws;
  float4* h4 = (float4*)(ws + (size_t)N * 4);
  float4* s4s = (float4*)(ws + (size_t)N * 8);
  float* aggr = ws + (size_t)N * 12;
  int* idxs = (int*)(ws + (size_t)N * 20);
  int* hist = idxs + N;
  int* cnt2 = hist + NBUCK;
  int* offs = cnt2 + NBUCK;
  unsigned short* pidx = (unsigned short*)(offs + NBUCK);

  zero_kernel<<<1, 256, 0, stream>>>(hist, cnt2);
  prep_kernel<<<N / 64, 64, 0, stream>>>(x, Ws, bs, Wh, bh, s4, h4, hist);
  scan_kernel<<<1, 256, 0, stream>>>(hist, offs);
  scatter_kernel<<<N / 64, 64, 0, stream>>>(s4, offs, cnt2, s4s, idxs);
  knn_kernel<<<(N / 256) * JS, 256, 0, stream>>>(s4s, pidx);
  merge_kernel<<<N / 256, 256, 0, stream>>>(s4s, idxs, h4, pidx, aggr);
  out_kernel<<<N / 64, 64, 0, stream>>>(x, aggr, Wo1, Wo2, bo2, Wb, bb, out);
}

// Round 3
// 345.781 us; speedup vs baseline: 1.7503x; 1.7503x over previous
//
#include <hip/hip_runtime.h>
#include <math.h>

#define N 16384
#define D 23
#define K 16
#define NBUCK 2048
#define XRANGE 8.0f
#define BSCALE 128.0f        // NBUCK / (2*XRANGE)
#define DLT 0.0078125f       // bucket width = within-bucket x-disorder slack

__device__ __forceinline__ int bucket_of(float x) {
  int b = (int)((x + XRANGE) * BSCALE);
  return b < 0 ? 0 : (b > NBUCK - 1 ? NBUCK - 1 : b);
}

// Sorted ascending insert of (d2, jj) into register lists vald/vali (K deep).
// Safe for any d2: no-op when d2 >= vald[K-1] (ck init carries the guard).
#define TOPK_INSERT(vald, vali, d2v, jjv)                          \
  {                                                                \
    bool ck = (d2v) < vald[K - 1];                                 \
    _Pragma("unroll") for (int k = K - 1; k >= 0; --k) {           \
      bool ckm1 = (k > 0) ? ((d2v) < vald[k - 1]) : false;         \
      float nv = ckm1 ? vald[k - 1] : (ck ? (d2v) : vald[k]);      \
      int ni = ckm1 ? vali[k - 1] : (ck ? (jjv) : vali[k]);        \
      vald[k] = nv;                                                \
      vali[k] = ni;                                                \
      ck = ckm1;                                                   \
    }                                                              \
  }

// ---------------------------------------------------------------------------
// Kernel 0: zero bucket counters
// ---------------------------------------------------------------------------
__global__ __launch_bounds__(256) void zero_kernel(int* __restrict__ hist,
                                                   int* __restrict__ cnt2) {
  for (int t = threadIdx.x; t < NBUCK; t += 256) {
    hist[t] = 0;
    cnt2[t] = 0;
  }
}

// ---------------------------------------------------------------------------
// Kernel 1: s = x@W_s + b_s, h = x@W_h + b_h; pack s4={sx,sy,sz,sq}, h4;
//           histogram of x-buckets. (numerics identical to prior rounds)
// ---------------------------------------------------------------------------
__global__ __launch_bounds__(64) void prep_kernel(
    const float* __restrict__ x, const float* __restrict__ Ws,
    const float* __restrict__ bs, const float* __restrict__ Wh,
    const float* __restrict__ bh, float4* __restrict__ s4,
    float4* __restrict__ h4, int* __restrict__ hist) {
  __shared__ float lWs[D * 3], lWh[D * 3], lbs[3], lbh[3];
  for (int t = threadIdx.x; t < D * 3; t += 64) {
    lWs[t] = Ws[t];
    lWh[t] = Wh[t];
  }
  if (threadIdx.x < 3) {
    lbs[threadIdx.x] = bs[threadIdx.x];
    lbh[threadIdx.x] = bh[threadIdx.x];
  }
  __syncthreads();

  int i = blockIdx.x * 64 + threadIdx.x;
  float a0 = 0.f, a1 = 0.f, a2 = 0.f;
  float g0 = 0.f, g1 = 0.f, g2 = 0.f;
#pragma unroll
  for (int d = 0; d < D; ++d) {
    float xv = x[i * D + d];
    a0 = fmaf(xv, lWs[d * 3 + 0], a0);
    a1 = fmaf(xv, lWs[d * 3 + 1], a1);
    a2 = fmaf(xv, lWs[d * 3 + 2], a2);
    g0 = fmaf(xv, lWh[d * 3 + 0], g0);
    g1 = fmaf(xv, lWh[d * 3 + 1], g1);
    g2 = fmaf(xv, lWh[d * 3 + 2], g2);
  }
  float s0 = __fadd_rn(a0, lbs[0]);
  float s1 = __fadd_rn(a1, lbs[1]);
  float s2 = __fadd_rn(a2, lbs[2]);
  float sq = fmaf(s2, s2, fmaf(s1, s1, __fmul_rn(s0, s0)));
  s4[i] = make_float4(s0, s1, s2, sq);
  h4[i] = make_float4(__fadd_rn(g0, lbh[0]), __fadd_rn(g1, lbh[1]),
                      __fadd_rn(g2, lbh[2]), 0.f);
  atomicAdd(&hist[bucket_of(s0)], 1);
}

// ---------------------------------------------------------------------------
// Kernel 2: exclusive prefix sum of hist[2048] -> offs[2048]. One block.
// ---------------------------------------------------------------------------
__global__ __launch_bounds__(256) void scan_kernel(const int* __restrict__ hist,
                                                   int* __restrict__ offs) {
  __shared__ int tsum[256];
  int t = threadIdx.x;
  int loc[8];
  int s = 0;
#pragma unroll
  for (int j = 0; j < 8; ++j) {
    loc[j] = hist[t * 8 + j];
    s += loc[j];
  }
  tsum[t] = s;
  __syncthreads();
  for (int off = 1; off < 256; off <<= 1) {
    int v = (t >= off) ? tsum[t - off] : 0;
    __syncthreads();
    tsum[t] += v;
    __syncthreads();
  }
  int base = tsum[t] - s;  // exclusive
#pragma unroll
  for (int j = 0; j < 8; ++j) {
    offs[t * 8 + j] = base;
    base += loc[j];
  }
}

// ---------------------------------------------------------------------------
// Kernel 3: scatter into contiguous x-sorted layout (+ sorted h, orig index)
// ---------------------------------------------------------------------------
__global__ __launch_bounds__(64) void scatter_kernel(
    const float4* __restrict__ s4, const float4* __restrict__ h4,
    const int* __restrict__ offs, int* __restrict__ cnt2,
    float4* __restrict__ s4s, float4* __restrict__ h4s,
    int* __restrict__ idxs) {
  int i = blockIdx.x * 64 + threadIdx.x;
  float4 s = s4[i];
  int b = bucket_of(s.x);
  int pos = offs[b] + atomicAdd(&cnt2[b], 1);
  s4s[pos] = s;
  h4s[pos] = h4[i];
  idxs[pos] = i;
}

// ---------------------------------------------------------------------------
// Kernel 4: kNN + aggregate, ONE QUERY PER WAVE. 64 lanes scan the query's
// x-window [x-r, x+r] (stride-64 coalesced), each lane keeps a private
// top-16 of its stride; exact cross-lane merge by 16 min-extractions; fused
// weight/gather/mean/max aggregation on lanes 0..15.
// Exactness: r accepted only when count(d2<=r^2) >= 16 (so the true top-16
// lies inside the window); tau = min-over-groups(max-of-16) of the first 64
// candidates is provably >= true 16th-smallest d2, so the tau insert gate
// never drops a true neighbor. Final iteration falls back to full scan.
// ---------------------------------------------------------------------------
__global__ __launch_bounds__(256) void knn_kernel(
    const float4* __restrict__ s4s, const float4* __restrict__ h4s,
    const int* __restrict__ idxs, float* __restrict__ aggr) {
  int lane = threadIdx.x & 63;
  int P = blockIdx.x * 4 + (threadIdx.x >> 6);  // sorted query position
  float4 si = s4s[P];
  float sqi = si.w;
  // Gaussian-density 16-NN radius estimate: 1.25 * 0.154 * exp(|s|^2/6)
  float r = 0.1925f * __expf(sqi * 0.16666667f);

  float vd[K];
  int vi[K];

  for (int it = 0; it < 12; ++it) {
    if (it == 11) r = 1e18f;  // exactness fallback: full scan
    float r2 = __fmul_rn(r, r);
    float bxr = si.x + r, bxl = si.x - r;
    float brkr = bxr + DLT, brkl = bxl - DLT;  // bucket-disorder slack
#pragma unroll
    for (int k = 0; k < K; ++k) {
      vd[k] = INFINITY;
      vi[k] = 0;
    }
    int cnt = 0;
    float tau = INFINITY;
    bool first = true;
    // ---- right walk (includes self at lane 0) ----
    for (int p0 = P; p0 < N; p0 += 64) {
      int p = p0 + lane;
      bool in = (p < N);
      float4 sj = s4s[in ? p : (N - 1)];
      float xj = in ? sj.x : INFINITY;
      float dot = fmaf(si.z, sj.z, fmaf(si.y, sj.y, __fmul_rn(si.x, sj.x)));
      float d2 = __fsub_rn(__fadd_rn(sqi, sj.w), __fmul_rn(2.0f, dot));
      bool pred = in && (xj <= bxr);
      if (pred && d2 <= r2) ++cnt;
      float d2g = pred ? d2 : INFINITY;
      int pg = pred ? p : 0;
      if (first) {
        TOPK_INSERT(vd, vi, d2g, pg);
        float gm = d2g;  // tau = min over 4 groups of (max of 16 lanes)
        gm = fmaxf(gm, __shfl_xor(gm, 1));
        gm = fmaxf(gm, __shfl_xor(gm, 2));
        gm = fmaxf(gm, __shfl_xor(gm, 4));
        gm = fmaxf(gm, __shfl_xor(gm, 8));
        gm = fminf(gm, __shfl_xor(gm, 16));
        gm = fminf(gm, __shfl_xor(gm, 32));
        tau = gm;
        first = false;
      } else if (d2g <= tau && d2g < vd[K - 1]) {
        TOPK_INSERT(vd, vi, d2g, pg);
      }
      if (__all(xj > brkr)) break;
    }
    // ---- left walk ----
    for (int p0 = P - 1; p0 >= 0; p0 -= 64) {
      int p = p0 - lane;
      bool in = (p >= 0);
      float4 sj = s4s[in ? p : 0];
      float xj = in ? sj.x : -INFINITY;
      float dot = fmaf(si.z, sj.z, fmaf(si.y, sj.y, __fmul_rn(si.x, sj.x)));
      float d2 = __fsub_rn(__fadd_rn(sqi, sj.w), __fmul_rn(2.0f, dot));
      bool pred = in && (xj >= bxl);
      if (pred && d2 <= r2) ++cnt;
      float d2g = pred ? d2 : INFINITY;
      int pg = pred ? p : 0;
      if (d2g <= tau && d2g < vd[K - 1]) {
        TOPK_INSERT(vd, vi, d2g, pg);
      }
      if (__all(xj < brkl)) break;
    }
    // wave-total count
    cnt += __shfl_xor(cnt, 1);
    cnt += __shfl_xor(cnt, 2);
    cnt += __shfl_xor(cnt, 4);
    cnt += __shfl_xor(cnt, 8);
    cnt += __shfl_xor(cnt, 16);
    cnt += __shfl_xor(cnt, 32);
    if (cnt >= K) break;
    r = __fmul_rn(r, 1.45f);
  }

  // ---- exact merge: 16 cross-lane min-extractions (idx tie-break) ----
  float sel_d = 0.f;
  int sel_i = 0;
#pragma unroll
  for (int e = 0; e < K; ++e) {
    float m = vd[0];
    int mi = vi[0];
#pragma unroll
    for (int s = 1; s < 64; s <<= 1) {
      float om = __shfl_xor(m, s);
      int oi = __shfl_xor(mi, s);
      if (om < m || (om == m && oi < mi)) {
        m = om;
        mi = oi;
      }
    }
    if (vd[0] == m && vi[0] == mi) {  // winner lane pops its head
#pragma unroll
      for (int k = 0; k < K - 1; ++k) {
        vd[k] = vd[k + 1];
        vi[k] = vi[k + 1];
      }
      vd[K - 1] = INFINITY;
    }
    if (lane == e) {
      sel_d = m;
      sel_i = mi;
    }
  }

  // ---- fused aggregation on lanes 0..15 ----
  if (lane < K) {
    float d2c = fmaxf(sel_d, 0.f);
    float w = expf(-10.0f * d2c);
    float4 hh = h4s[sel_i];
    float m0 = __fmul_rn(hh.x, w);
    float m1 = __fmul_rn(hh.y, w);
    float m2 = __fmul_rn(hh.z, w);
    float x0 = m0, x1 = m1, x2 = m2;
#pragma unroll
    for (int s = 1; s < K; s <<= 1) {
      m0 += __shfl_xor(m0, s);
      m1 += __shfl_xor(m1, s);
      m2 += __shfl_xor(m2, s);
      x0 = fmaxf(x0, __shfl_xor(x0, s));
      x1 = fmaxf(x1, __shfl_xor(x1, s));
      x2 = fmaxf(x2, __shfl_xor(x2, s));
    }
    if (lane == 0) {
      int oq = idxs[P];
      float* a = &aggr[(size_t)oq * 8];
      const float inv = 1.0f / 16.0f;
      a[0] = m0 * inv;
      a[1] = m1 * inv;
      a[2] = m2 * inv;
      a[3] = x0;
      a[4] = x1;
      a[5] = x2;
    }
  }
}

// ---------------------------------------------------------------------------
// Kernel 5: latent = x@W_o1 + (aggr@W_o2 + b_o2); beta = clip(sigmoid(...))
// ---------------------------------------------------------------------------
__global__ __launch_bounds__(64) void out_kernel(
    const float* __restrict__ x, const float* __restrict__ aggr,
    const float* __restrict__ Wo1, const float* __restrict__ Wo2,
    const float* __restrict__ bo2, const float* __restrict__ Wb,
    const float* __restrict__ bb, float* __restrict__ out) {
  __shared__ float lWo1[D * D];
  __shared__ float lWo2[6 * D];
  __shared__ float lbo2[D], lWb[D];
  __shared__ float lbb;
  for (int t = threadIdx.x; t < D * D; t += 64) lWo1[t] = Wo1[t];
  for (int t = threadIdx.x; t < 6 * D; t += 64) lWo2[t] = Wo2[t];
  if (threadIdx.x < D) {
    lbo2[threadIdx.x] = bo2[threadIdx.x];
    lWb[threadIdx.x] = Wb[threadIdx.x];
  }
  if (threadIdx.x == 0) lbb = bb[0];
  __syncthreads();

  int i = blockIdx.x * 64 + threadIdx.x;
  float xr[D];
#pragma unroll
  for (int d = 0; d < D; ++d) xr[d] = x[i * D + d];
  float ag[6];
#pragma unroll
  for (int p = 0; p < 6; ++p) ag[p] = aggr[(size_t)i * 8 + p];

  float z = 0.f;
#pragma unroll
  for (int o = 0; o < D; ++o) {
    float a = 0.f;
#pragma unroll
    for (int d = 0; d < D; ++d) a = fmaf(xr[d], lWo1[d * D + o], a);
    float b2 = 0.f;
#pragma unroll
    for (int p = 0; p < 6; ++p) b2 = fmaf(ag[p], lWo2[p * D + o], b2);
    b2 = __fadd_rn(b2, lbo2[o]);
    float lat = __fadd_rn(a, b2);
    out[(size_t)N + (size_t)i * D + o] = lat;
    z = fmaf(lat, lWb[o], z);
  }
  z = __fadd_rn(z, lbb);
  float beta = 1.0f / (1.0f + expf(-z));
  beta = fminf(fmaxf(beta, 1e-6f), 1.0f - 1e-6f);
  out[i] = beta;
}

// ---------------------------------------------------------------------------
extern "C" void kernel_launch(void* const* d_in, const int* in_sizes, int n_in,
                              void* d_out, int out_size, void* d_ws,
                              size_t ws_size, hipStream_t stream) {
  const float* x = (const float*)d_in[0];
  const float* Ws = (const float*)d_in[1];
  const float* bs = (const float*)d_in[2];
  const float* Wh = (const float*)d_in[3];
  const float* bh = (const float*)d_in[4];
  const float* Wo1 = (const float*)d_in[5];
  const float* Wo2 = (const float*)d_in[6];
  const float* bo2 = (const float*)d_in[7];
  const float* Wb = (const float*)d_in[8];
  const float* bb = (const float*)d_in[9];
  float* out = (float*)d_out;

  // ws layout (floats): s4[N*4] | h4[N*4] | s4s[N*4] | h4s[N*4] | aggr[N*8] |
  // idxs[N]i | hist[2048]i | cnt2[2048]i | offs[2048]i      (~1.7 MB)
  float* ws = (float*)d_ws;
  float4* s4 = (float4*)ws;
  float4* h4 = (float4*)(ws + (size_t)N * 4);
  float4* s4s = (float4*)(ws + (size_t)N * 8);
  float4* h4s = (float4*)(ws + (size_t)N * 12);
  float* aggr = ws + (size_t)N * 16;
  int* idxs = (int*)(ws + (size_t)N * 24);
  int* hist = idxs + N;
  int* cnt2 = hist + NBUCK;
  int* offs = cnt2 + NBUCK;

  zero_kernel<<<1, 256, 0, stream>>>(hist, cnt2);
  prep_kernel<<<N / 64, 64, 0, stream>>>(x, Ws, bs, Wh, bh, s4, h4, hist);
  scan_kernel<<<1, 256, 0, stream>>>(hist, offs);
  scatter_kernel<<<N / 64, 64, 0, stream>>>(s4, h4, offs, cnt2, s4s, h4s,
                                            idxs);
  knn_kernel<<<N / 4, 256, 0, stream>>>(s4s, h4s, idxs, aggr);
  out_kernel<<<N / 64, 64, 0, stream>>>(x, aggr, Wo1, Wo2, bo2, Wb, bb, out);
}